// Round 3
// baseline (696.594 us; speedup 1.0000x reference)
//
#include <hip/hip_runtime.h>

#define NN 100000
#define NE 600000
#define NL 200000

// NOTE: harness materializes integer inputs as int32 (NOT the reference's int64).
// edge_index is [2][NE] int32: src = ei[0..NE), dst = ei[NE..2NE).

// ---------------- weight transpose: WT[k][o] = W[o][k] ----------------
__global__ void k_transpose(const float* __restrict__ W1l, const float* __restrict__ W1r,
                            const float* __restrict__ W2l, const float* __restrict__ W2r,
                            float* __restrict__ WT1, float* __restrict__ WT2){
  int i = blockIdx.x*256 + threadIdx.x;
  if (i < 16384)      { int k=i>>7, o=i&127;                 WT1[i] = W1l[o*128+k]; }
  else if (i < 32768) { int j=i-16384; int k=j>>7, o=j&127;  WT1[i] = W1r[o*128+k]; }
  else if (i < 40960) { int j=i-32768; int k=j>>6, o=j&63;   WT2[j] = W2l[o*128+k]; }
  else if (i < 49152) { int j=i-40960; int k=j>>6, o=j&63;   WT2[8192+j] = W2r[o*128+k]; }
}

// ---------------- CSR build ----------------
__global__ void k_count(const int* __restrict__ dst, int* __restrict__ deg){
  int e = blockIdx.x*256 + threadIdx.x;
  if (e < NE) atomicAdd(&deg[dst[e]], 1);
}

__global__ void k_scan_partial(const int* __restrict__ deg, int* __restrict__ bsum){
  __shared__ int s[256];
  int i = blockIdx.x*256 + threadIdx.x;
  int t = threadIdx.x;
  s[t] = (i < NN) ? deg[i] : 0;
  __syncthreads();
  for (int st=128; st>0; st>>=1){ if (t<st) s[t]+=s[t+st]; __syncthreads(); }
  if (t==0) bsum[blockIdx.x]=s[0];
}

__global__ void k_scan_bsum(int* __restrict__ bsum, int nb){
  __shared__ int s[512];
  int t = threadIdx.x;
  int orig = (t<nb)?bsum[t]:0;
  s[t]=orig; __syncthreads();
  for (int st=1; st<512; st<<=1){
    int v = (t>=st)? s[t-st] : 0;
    __syncthreads();
    s[t] += v;
    __syncthreads();
  }
  if (t<nb) bsum[t] = s[t]-orig;   // exclusive prefix of block sums
}

__global__ void k_scan_final(const int* __restrict__ deg, const int* __restrict__ bsum,
                             int* __restrict__ rowptr, int* __restrict__ cursor){
  __shared__ int s[256];
  int i = blockIdx.x*256 + threadIdx.x;
  int t = threadIdx.x;
  int orig = (i<NN)?deg[i]:0;
  s[t]=orig; __syncthreads();
  for (int st=1; st<256; st<<=1){
    int v = (t>=st)? s[t-st] : 0;
    __syncthreads();
    s[t]+=v;
    __syncthreads();
  }
  int excl = s[t]-orig + bsum[blockIdx.x];
  if (i<NN){ rowptr[i]=excl; cursor[i]=excl; }
  if (i==0 && blockIdx.x==0) rowptr[NN]=NE;
}

__global__ void k_fill(const int* __restrict__ ei, int* __restrict__ cursor,
                       int* __restrict__ csr){
  int e = blockIdx.x*256 + threadIdx.x;
  if (e < NE){
    int p = atomicAdd(&cursor[ei[NE+e]], 1);
    csr[p] = ei[e];
  }
}

// ---------------- fused SAGE layer: out = act(mean_agg(feat)@Wl^T + feat@Wr^T + b) ----------------
// WT layout: [128][DOUT] for Wl, then [128][DOUT] for Wr (k-major, coalesced over o).
#define SSTR 33
template<int DOUT, bool RELU>
__global__ __launch_bounds__(256) void k_sage(
    const float* __restrict__ feat,
    const int* __restrict__ rowptr, const int* __restrict__ csr,
    const float* __restrict__ WT, const float* __restrict__ bias,
    float* __restrict__ out)
{
  __shared__ float sA[128*SSTR + 32];   // [k][r] transposed, stride 33
  __shared__ float sX[128*SSTR + 32];
  int tid = threadIdx.x;
  int m0 = blockIdx.x*32;

  // Phase A: aggregate 32 nodes into LDS (2 nodes in parallel, 128 threads each)
  {
    int half = tid >> 7;      // 0/1
    int d    = tid & 127;
    for (int r2=0; r2<16; ++r2){
      int r = r2*2 + half;
      int v = m0 + r;
      int s = rowptr[v], e = rowptr[v+1];
      float sum = 0.f;
      for (int j=s; j<e; ++j)
        sum += feat[(size_t)csr[j]*128 + d];
      sA[d*SSTR + r] = sum / fmaxf((float)(e-s), 1.0f);
      sX[d*SSTR + r] = feat[(size_t)v*128 + d];
    }
  }
  __syncthreads();

  // Phase B: register-tiled GEMM, 32 rows x DOUT cols
  constexpr int CG = DOUT/4;        // col groups: 32 (DOUT=128) or 16 (DOUT=64)
  constexpr int RT = 32*CG/256;     // rows/thread: 4 or 2
  int tx = tid % CG, ty = tid / CG;
  int o0 = tx*4, r0 = ty*RT;
  float acc[RT][4] = {};
  const float* Wl = WT;
  const float* Wr = WT + 128*DOUT;
  for (int k=0; k<128; ++k){
    float a[RT], xv[RT];
#pragma unroll
    for (int r=0; r<RT; ++r){
      a[r]  = sA[k*SSTR + r0 + r];
      xv[r] = sX[k*SSTR + r0 + r];
    }
    float4 wl = *(const float4*)(Wl + k*DOUT + o0);
    float4 wr = *(const float4*)(Wr + k*DOUT + o0);
    float wlv[4] = {wl.x,wl.y,wl.z,wl.w};
    float wrv[4] = {wr.x,wr.y,wr.z,wr.w};
#pragma unroll
    for (int r=0; r<RT; ++r)
#pragma unroll
      for (int c=0; c<4; ++c)
        acc[r][c] += a[r]*wlv[c] + xv[r]*wrv[c];
  }
  float4 bb = *(const float4*)(bias + o0);
  float bv[4] = {bb.x,bb.y,bb.z,bb.w};
#pragma unroll
  for (int r=0; r<RT; ++r){
    float t0 = acc[r][0]+bv[0], t1 = acc[r][1]+bv[1];
    float t2 = acc[r][2]+bv[2], t3 = acc[r][3]+bv[3];
    if (RELU){
      t0 = fmaxf(t0,0.f); t1 = fmaxf(t1,0.f);
      t2 = fmaxf(t2,0.f); t3 = fmaxf(t3,0.f);
    }
    float4 v; v.x=t0; v.y=t1; v.z=t2; v.w=t3;
    *(float4*)&out[(size_t)(m0+r0+r)*DOUT + o0] = v;
  }
}

// ---------------- decode: out[p] = dot(z[a], z[b]) over 64 dims ----------------
__global__ __launch_bounds__(256) void k_decode(const int* __restrict__ eli,
                         const float* __restrict__ z, float* __restrict__ out){
  int t = blockIdx.x*256 + threadIdx.x;
  int p = t >> 4;
  int l = t & 15;
  if (p >= NL) return;
  int a = eli[p];
  int b = eli[NL + p];
  float4 za = *(const float4*)&z[(size_t)a*64 + l*4];
  float4 zb = *(const float4*)&z[(size_t)b*64 + l*4];
  float d = za.x*zb.x + za.y*zb.y + za.z*zb.z + za.w*zb.w;
#pragma unroll
  for (int m=1; m<16; m<<=1) d += __shfl_xor(d, m, 64);
  if (l==0) out[p] = d;
}

// ---------------- fallback: report ws_size via absmax if scratch too small ----------------
__global__ void k_fallback(float* __restrict__ out, float val){
  int i = blockIdx.x*256 + threadIdx.x;
  if (i < NL) out[i] = val;
}

extern "C" void kernel_launch(void* const* d_in, const int* in_sizes, int n_in,
                              void* d_out, int out_size, void* d_ws, size_t ws_size,
                              hipStream_t stream){
  const float* x   = (const float*)d_in[0];
  const int* ei    = (const int*)d_in[1];    // int32! [2][NE]
  const int* eli   = (const int*)d_in[2];    // int32! [2][NL]
  const float* W1l = (const float*)d_in[3];
  const float* b1  = (const float*)d_in[4];
  const float* W1r = (const float*)d_in[5];
  const float* W2l = (const float*)d_in[6];
  const float* b2  = (const float*)d_in[7];
  const float* W2r = (const float*)d_in[8];
  float* out = (float*)d_out;
  (void)in_sizes; (void)n_in; (void)out_size;

  char* w = (char*)d_ws;
  size_t off = 0;
  auto take = [&](size_t bytes)->char*{
    char* p = w + off; off = (off + bytes + 255) & ~(size_t)255; return p;
  };
  int* deg    = (int*)take((size_t)NN*4);
  int* rowptr = (int*)take((size_t)(NN+1)*4);
  int* cursor = (int*)take((size_t)NN*4);
  int* bsum   = (int*)take(1024*4);
  int* csr    = (int*)take((size_t)NE*4);
  float* WT1  = (float*)take((size_t)2*128*128*4);
  float* WT2  = (float*)take((size_t)2*128*64*4);
  float* h    = (float*)take((size_t)NN*128*4);
  float* z    = (float*)take((size_t)NN*64*4);

  if (off > ws_size){
    // graceful, decodable failure: output = ws_size in MB
    k_fallback<<<(NL+255)/256,256,0,stream>>>(out, (float)(ws_size>>20));
    return;
  }

  hipMemsetAsync(deg, 0, (size_t)NN*4, stream);
  k_transpose<<<192,256,0,stream>>>(W1l,W1r,W2l,W2r,WT1,WT2);
  k_count<<<(NE+255)/256,256,0,stream>>>(ei+NE, deg);
  int nb = (NN+255)/256;   // 391
  k_scan_partial<<<nb,256,0,stream>>>(deg,bsum);
  k_scan_bsum<<<1,512,0,stream>>>(bsum,nb);
  k_scan_final<<<nb,256,0,stream>>>(deg,bsum,rowptr,cursor);
  k_fill<<<(NE+255)/256,256,0,stream>>>(ei,cursor,csr);

  // layer 1: h = relu(agg(x)@W1l^T + x@W1r^T + b1)
  k_sage<128,true><<<NN/32,256,0,stream>>>(x, rowptr, csr, WT1, b1, h);
  // layer 2: z = agg(h)@W2l^T + h@W2r^T + b2
  k_sage<64,false><<<NN/32,256,0,stream>>>(h, rowptr, csr, WT2, b2, z);
  // decode
  k_decode<<<(NL*16)/256,256,0,stream>>>(eli,z,out);
}

// Round 4
// 383.497 us; speedup vs baseline: 1.8164x; 1.8164x over previous
//
#include <hip/hip_runtime.h>

#define NN 100000
#define NE 600000
#define NL 200000

// NOTE: harness materializes integer inputs as int32 (NOT the reference's int64).
// edge_index is [2][NE] int32: src = ei[0..NE), dst = ei[NE..2NE).

// ---------------- weight transpose: WT[k][o] = W[o][k] ----------------
__global__ void k_transpose(const float* __restrict__ W1l, const float* __restrict__ W1r,
                            const float* __restrict__ W2l, const float* __restrict__ W2r,
                            float* __restrict__ WT1, float* __restrict__ WT2){
  int i = blockIdx.x*256 + threadIdx.x;
  if (i < 16384)      { int k=i>>7, o=i&127;                 WT1[i] = W1l[o*128+k]; }
  else if (i < 32768) { int j=i-16384; int k=j>>7, o=j&127;  WT1[i] = W1r[o*128+k]; }
  else if (i < 40960) { int j=i-32768; int k=j>>6, o=j&63;   WT2[j] = W2l[o*128+k]; }
  else if (i < 49152) { int j=i-40960; int k=j>>6, o=j&63;   WT2[8192+j] = W2r[o*128+k]; }
}

// ---------------- CSR build ----------------
__global__ void k_count(const int* __restrict__ dst, int* __restrict__ deg){
  int e = blockIdx.x*256 + threadIdx.x;
  if (e < NE) atomicAdd(&deg[dst[e]], 1);
}

__global__ void k_scan_partial(const int* __restrict__ deg, int* __restrict__ bsum){
  __shared__ int s[256];
  int i = blockIdx.x*256 + threadIdx.x;
  int t = threadIdx.x;
  s[t] = (i < NN) ? deg[i] : 0;
  __syncthreads();
  for (int st=128; st>0; st>>=1){ if (t<st) s[t]+=s[t+st]; __syncthreads(); }
  if (t==0) bsum[blockIdx.x]=s[0];
}

__global__ void k_scan_bsum(int* __restrict__ bsum, int nb){
  __shared__ int s[512];
  int t = threadIdx.x;
  int orig = (t<nb)?bsum[t]:0;
  s[t]=orig; __syncthreads();
  for (int st=1; st<512; st<<=1){
    int v = (t>=st)? s[t-st] : 0;
    __syncthreads();
    s[t] += v;
    __syncthreads();
  }
  if (t<nb) bsum[t] = s[t]-orig;   // exclusive prefix of block sums
}

__global__ void k_scan_final(const int* __restrict__ deg, const int* __restrict__ bsum,
                             int* __restrict__ rowptr, int* __restrict__ cursor){
  __shared__ int s[256];
  int i = blockIdx.x*256 + threadIdx.x;
  int t = threadIdx.x;
  int orig = (i<NN)?deg[i]:0;
  s[t]=orig; __syncthreads();
  for (int st=1; st<256; st<<=1){
    int v = (t>=st)? s[t-st] : 0;
    __syncthreads();
    s[t]+=v;
    __syncthreads();
  }
  int excl = s[t]-orig + bsum[blockIdx.x];
  if (i<NN){ rowptr[i]=excl; cursor[i]=excl; }
  if (i==0 && blockIdx.x==0) rowptr[NN]=NE;
}

__global__ void k_fill(const int* __restrict__ ei, int* __restrict__ cursor,
                       int* __restrict__ csr){
  int e = blockIdx.x*256 + threadIdx.x;
  if (e < NE){
    int p = atomicAdd(&cursor[ei[NE+e]], 1);
    csr[p] = ei[e];
  }
}

// ---------------- fused SAGE layer: out = act(mean_agg(feat)@Wl^T + feat@Wr^T + b) ----------------
// WT layout: [128][DOUT] for Wl, then [128][DOUT] for Wr (k-major, coalesced over o).
#define SSTR 34
template<int DOUT, bool RELU>
__global__ __launch_bounds__(256) void k_sage(
    const float* __restrict__ feat,
    const int* __restrict__ rowptr, const int* __restrict__ csr,
    const float* __restrict__ WT, const float* __restrict__ bias,
    float* __restrict__ out)
{
  __shared__ float sA[128*SSTR];   // [k][r] transposed, stride 34
  __shared__ float sX[128*SSTR];
  int tid = threadIdx.x;
  int m0 = blockIdx.x*32;

  // Phase A: wave-per-row gather. Lane covers dims {2*lane, 2*lane+1} via float2.
  // Neighbor loop unrolled x4 with uniform float masks (no serial tail).
  {
    int wave = tid >> 6;
    int lane = tid & 63;
    for (int rr=0; rr<8; ++rr){
      int r = wave*8 + rr;
      int v = m0 + r;
      int s = __builtin_amdgcn_readfirstlane(rowptr[v]);
      int e = __builtin_amdgcn_readfirstlane(rowptr[v+1]);
      float s0 = 0.f, s1 = 0.f;
      for (int j=s; j<e; j+=4){
        int e1 = e-1;
        int n0 = csr[j];
        int n1 = csr[j+1<e1?j+1:e1];
        int n2 = csr[j+2<e1?j+2:e1];
        int n3 = csr[j+3<e1?j+3:e1];
        float m1 = (j+1<e)?1.f:0.f;
        float m2 = (j+2<e)?1.f:0.f;
        float m3 = (j+3<e)?1.f:0.f;
        float2 f0 = *(const float2*)&feat[(size_t)n0*128 + 2*lane];
        float2 f1 = *(const float2*)&feat[(size_t)n1*128 + 2*lane];
        float2 f2 = *(const float2*)&feat[(size_t)n2*128 + 2*lane];
        float2 f3 = *(const float2*)&feat[(size_t)n3*128 + 2*lane];
        s0 += f0.x; s1 += f0.y;
        s0 += f1.x*m1; s1 += f1.y*m1;
        s0 += f2.x*m2; s1 += f2.y*m2;
        s0 += f3.x*m3; s1 += f3.y*m3;
      }
      float inv = 1.f / fmaxf((float)(e-s), 1.f);
      float2 xv = *(const float2*)&feat[(size_t)v*128 + 2*lane];
      sA[(2*lane  )*SSTR + r] = s0*inv;
      sA[(2*lane+1)*SSTR + r] = s1*inv;
      sX[(2*lane  )*SSTR + r] = xv.x;
      sX[(2*lane+1)*SSTR + r] = xv.y;
    }
  }
  __syncthreads();

  // Phase B: register-tiled GEMM, 32 rows x DOUT cols
  constexpr int CG = DOUT/4;        // col groups: 32 (DOUT=128) or 16 (DOUT=64)
  constexpr int RT = 32*CG/256;     // rows/thread: 4 or 2
  int tx = tid % CG, ty = tid / CG;
  int o0 = tx*4, r0 = ty*RT;        // r0 even -> float2-aligned LDS reads
  float acc[RT][4] = {};
  const float* Wl = WT;
  const float* Wr = WT + 128*DOUT;
  for (int k=0; k<128; ++k){
    float a[RT], xv[RT];
#pragma unroll
    for (int r=0; r<RT; r+=2){
      float2 av = *(const float2*)&sA[k*SSTR + r0 + r];
      float2 ev = *(const float2*)&sX[k*SSTR + r0 + r];
      a[r] = av.x; a[r+1] = av.y;
      xv[r] = ev.x; xv[r+1] = ev.y;
    }
    float4 wl = *(const float4*)(Wl + k*DOUT + o0);
    float4 wr = *(const float4*)(Wr + k*DOUT + o0);
    float wlv[4] = {wl.x,wl.y,wl.z,wl.w};
    float wrv[4] = {wr.x,wr.y,wr.z,wr.w};
#pragma unroll
    for (int r=0; r<RT; ++r)
#pragma unroll
      for (int c=0; c<4; ++c)
        acc[r][c] += a[r]*wlv[c] + xv[r]*wrv[c];
  }
  float4 bb = *(const float4*)(bias + o0);
  float bv[4] = {bb.x,bb.y,bb.z,bb.w};
#pragma unroll
  for (int r=0; r<RT; ++r){
    float t0 = acc[r][0]+bv[0], t1 = acc[r][1]+bv[1];
    float t2 = acc[r][2]+bv[2], t3 = acc[r][3]+bv[3];
    if (RELU){
      t0 = fmaxf(t0,0.f); t1 = fmaxf(t1,0.f);
      t2 = fmaxf(t2,0.f); t3 = fmaxf(t3,0.f);
    }
    float4 v; v.x=t0; v.y=t1; v.z=t2; v.w=t3;
    *(float4*)&out[(size_t)(m0+r0+r)*DOUT + o0] = v;
  }
}

// ---------------- decode: out[p] = dot(z[a], z[b]) over 64 dims ----------------
__global__ __launch_bounds__(256) void k_decode(const int* __restrict__ eli,
                         const float* __restrict__ z, float* __restrict__ out){
  int t = blockIdx.x*256 + threadIdx.x;
  int p = t >> 4;
  int l = t & 15;
  if (p >= NL) return;
  int a = eli[p];
  int b = eli[NL + p];
  float4 za = *(const float4*)&z[(size_t)a*64 + l*4];
  float4 zb = *(const float4*)&z[(size_t)b*64 + l*4];
  float d = za.x*zb.x + za.y*zb.y + za.z*zb.z + za.w*zb.w;
#pragma unroll
  for (int m=1; m<16; m<<=1) d += __shfl_xor(d, m, 64);
  if (l==0) out[p] = d;
}

// ---------------- fallback: report ws_size via absmax if scratch too small ----------------
__global__ void k_fallback(float* __restrict__ out, float val){
  int i = blockIdx.x*256 + threadIdx.x;
  if (i < NL) out[i] = val;
}

extern "C" void kernel_launch(void* const* d_in, const int* in_sizes, int n_in,
                              void* d_out, int out_size, void* d_ws, size_t ws_size,
                              hipStream_t stream){
  const float* x   = (const float*)d_in[0];
  const int* ei    = (const int*)d_in[1];    // int32! [2][NE]
  const int* eli   = (const int*)d_in[2];    // int32! [2][NL]
  const float* W1l = (const float*)d_in[3];
  const float* b1  = (const float*)d_in[4];
  const float* W1r = (const float*)d_in[5];
  const float* W2l = (const float*)d_in[6];
  const float* b2  = (const float*)d_in[7];
  const float* W2r = (const float*)d_in[8];
  float* out = (float*)d_out;
  (void)in_sizes; (void)n_in; (void)out_size;

  char* w = (char*)d_ws;
  size_t off = 0;
  auto take = [&](size_t bytes)->char*{
    char* p = w + off; off = (off + bytes + 255) & ~(size_t)255; return p;
  };
  int* deg    = (int*)take((size_t)NN*4);
  int* rowptr = (int*)take((size_t)(NN+1)*4);
  int* cursor = (int*)take((size_t)NN*4);
  int* bsum   = (int*)take(1024*4);
  int* csr    = (int*)take((size_t)NE*4);
  float* WT1  = (float*)take((size_t)2*128*128*4);
  float* WT2  = (float*)take((size_t)2*128*64*4);
  float* h    = (float*)take((size_t)NN*128*4);
  float* z    = (float*)take((size_t)NN*64*4);

  if (off > ws_size){
    // graceful, decodable failure: output = ws_size in MB
    k_fallback<<<(NL+255)/256,256,0,stream>>>(out, (float)(ws_size>>20));
    return;
  }

  hipMemsetAsync(deg, 0, (size_t)NN*4, stream);
  k_transpose<<<192,256,0,stream>>>(W1l,W1r,W2l,W2r,WT1,WT2);
  k_count<<<(NE+255)/256,256,0,stream>>>(ei+NE, deg);
  int nb = (NN+255)/256;   // 391
  k_scan_partial<<<nb,256,0,stream>>>(deg,bsum);
  k_scan_bsum<<<1,512,0,stream>>>(bsum,nb);
  k_scan_final<<<nb,256,0,stream>>>(deg,bsum,rowptr,cursor);
  k_fill<<<(NE+255)/256,256,0,stream>>>(ei,cursor,csr);

  // layer 1: h = relu(agg(x)@W1l^T + x@W1r^T + b1)
  k_sage<128,true><<<NN/32,256,0,stream>>>(x, rowptr, csr, WT1, b1, h);
  // layer 2: z = agg(h)@W2l^T + h@W2r^T + b2
  k_sage<64,false><<<NN/32,256,0,stream>>>(h, rowptr, csr, WT2, b2, z);
  // decode
  k_decode<<<(NL*16)/256,256,0,stream>>>(eli,z,out);
}